// Round 1
// 1042.695 us; speedup vs baseline: 1.0116x; 1.0116x over previous
//
#include <hip/hip_runtime.h>
#include <stdint.h>

#define IN_DIM 1280
#define HID    5120
#define NROWS  8192        // 32*16*16
#define HW     256
#define XB_STRIDE (IN_DIM*HW)             // 327680
#define FEATS_ELEMS (2ull*NROWS*HID)      // 83886080 floats
#define RECON_ELEMS ((size_t)NROWS*IN_DIM) // 10485760 floats

#define CAND_CAP 80
#define CAND_MARGIN 0.015f

typedef __attribute__((ext_vector_type(8))) short bf16x8;
typedef __attribute__((ext_vector_type(4))) float f32x4;
typedef unsigned short ushort_t;

__device__ inline ushort_t f32_to_bf16(float f) {
    uint32_t u = __float_as_uint(f);
    u += 0x7fff + ((u >> 16) & 1);            // round-to-nearest-even
    return (ushort_t)(u >> 16);
}

__device__ inline void load_lds16(const void* g, void* l) {
    __builtin_amdgcn_global_load_lds(
        (const __attribute__((address_space(1))) uint32_t*)g,
        (__attribute__((address_space(3))) uint32_t*)l, 16, 0, 0);
}

// ---- K1a: x [32][1280][256] -> A_bf16 [n][c] + xT fp32 [n][c], n = b*256+hw ----
__global__ __launch_bounds__(256) void convertA(const float* __restrict__ x,
        ushort_t* __restrict__ Abf, float* __restrict__ xT) {
    __shared__ float s[32][33];
    const int c0 = blockIdx.x * 32, hw0 = blockIdx.y * 32, b = blockIdx.z;
    const int tx = threadIdx.x & 31, ty0 = threadIdx.x >> 5;
    const float* src = x + (size_t)b * XB_STRIDE;
    #pragma unroll
    for (int r = 0; r < 4; r++) {
        int c = c0 + ty0*4 + r;
        s[ty0*4+r][tx] = src[(size_t)c * HW + hw0 + tx];
    }
    __syncthreads();
    #pragma unroll
    for (int r = 0; r < 4; r++) {
        int hw = hw0 + ty0*4 + r;
        int n = b*256 + hw;
        float v = s[tx][ty0*4+r];
        Abf[(size_t)n * IN_DIM + c0 + tx] = f32_to_bf16(v);
        xT [(size_t)n * IN_DIM + c0 + tx] = v;
    }
}

// ---- K1b: W_enc [1280][5120] -> W_encT bf16 + fp32 [j][c] ----
__global__ __launch_bounds__(256) void convertB(const float* __restrict__ W,
        ushort_t* __restrict__ Wbf, float* __restrict__ Wf) {
    __shared__ float s[32][33];
    const int j0 = blockIdx.x * 32, c0 = blockIdx.y * 32;
    const int tx = threadIdx.x & 31, ty0 = threadIdx.x >> 5;
    #pragma unroll
    for (int r = 0; r < 4; r++) {
        int c = c0 + ty0*4 + r;
        s[ty0*4+r][tx] = W[(size_t)c * HID + j0 + tx];
    }
    __syncthreads();
    #pragma unroll
    for (int r = 0; r < 4; r++) {
        int j = j0 + ty0*4 + r;
        float v = s[tx][ty0*4+r];
        Wbf[(size_t)j * IN_DIM + c0 + tx] = f32_to_bf16(v);
        Wf [(size_t)j * IN_DIM + c0 + tx] = v;
    }
}

// ---- K1c: W_dec [5120][1280] fp32 -> bf16 (elementwise) ----
__global__ __launch_bounds__(256) void convert_Wdec(const float* __restrict__ W,
        ushort_t* __restrict__ out) {
    size_t i = ((size_t)blockIdx.x * 256 + threadIdx.x) * 4;
    float4 v = *(const float4*)&W[i];
    out[i+0] = f32_to_bf16(v.x);
    out[i+1] = f32_to_bf16(v.y);
    out[i+2] = f32_to_bf16(v.z);
    out[i+3] = f32_to_bf16(v.w);
}

// ---- K2: bf16 MFMA GEMM, approx enc = relu(A@W + b), global_load_lds staging ----
#define BM 128
#define BN 128
#define BK 32

__global__ __launch_bounds__(256) void encode_mfma(const ushort_t* __restrict__ A,
        const ushort_t* __restrict__ B, const float* __restrict__ b_enc,
        float* __restrict__ C) {
    __shared__ __align__(16) ushort_t As[BM*BK];   // [128 rows][32 k] = 8 KB
    __shared__ __align__(16) ushort_t Bs[BN*BK];
    const int n0 = blockIdx.x * BN;
    const int m0 = blockIdx.y * BM;
    const int t = threadIdx.x;
    const int lane = t & 63, w = t >> 6;
    const int mr0 = (w >> 1) * 64, nc0 = (w & 1) * 64;
    const int lm = lane & 15, lq = lane >> 4;
    const int srow_l = w*16 + (lane >> 2);
    const int skof   = (lane & 3) * 8;

    f32x4 acc[4][4];
    #pragma unroll
    for (int i = 0; i < 4; i++)
        #pragma unroll
        for (int j = 0; j < 4; j++)
            #pragma unroll
            for (int q = 0; q < 4; q++) acc[i][j][q] = 0.f;

    for (int k0 = 0; k0 < IN_DIM; k0 += BK) {
        #pragma unroll
        for (int h = 0; h < 2; h++) {
            const ushort_t* ga = &A[(size_t)(m0 + h*64 + srow_l)*IN_DIM + k0 + skof];
            const ushort_t* gb = &B[(size_t)(n0 + h*64 + srow_l)*IN_DIM + k0 + skof];
            load_lds16(ga, &As[(h*64 + w*16)*BK]);
            load_lds16(gb, &Bs[(h*64 + w*16)*BK]);
        }
        __syncthreads();
        bf16x8 af[4], bfr[4];
        #pragma unroll
        for (int mt = 0; mt < 4; mt++)
            af[mt] = *(const bf16x8*)&As[(mr0 + mt*16 + lm)*BK + lq*8];
        #pragma unroll
        for (int nt = 0; nt < 4; nt++)
            bfr[nt] = *(const bf16x8*)&Bs[(nc0 + nt*16 + lm)*BK + lq*8];
        #pragma unroll
        for (int mt = 0; mt < 4; mt++)
            #pragma unroll
            for (int nt = 0; nt < 4; nt++)
                acc[mt][nt] = __builtin_amdgcn_mfma_f32_16x16x32_bf16(af[mt], bfr[nt], acc[mt][nt], 0, 0, 0);
        __syncthreads();
    }
    #pragma unroll
    for (int mt = 0; mt < 4; mt++) {
        #pragma unroll
        for (int nt = 0; nt < 4; nt++) {
            int col = n0 + nc0 + nt*16 + lm;
            float bias = b_enc[col];
            #pragma unroll
            for (int r = 0; r < 4; r++) {
                int row = m0 + mr0 + mt*16 + lq*4 + r;
                float v = acc[mt][nt][r] + bias;
                C[(size_t)row*HID + col] = v > 0.f ? v : 0.f;
            }
        }
    }
}

// ---- K3: per-row approx-rank-32 threshold (binary search) + margin compaction ----
__global__ __launch_bounds__(256) void topk_approx(const float* __restrict__ E,
        int* __restrict__ cand_idx, int* __restrict__ cand_cnt) {
    const int n = blockIdx.x, t = threadIdx.x;
    const float* row = E + (size_t)n * HID;
    float v[20];
    #pragma unroll
    for (int r = 0; r < 20; r++) v[r] = row[t + 256*r];
    float mx = 0.f;
    #pragma unroll
    for (int r = 0; r < 20; r++) mx = fmaxf(mx, v[r]);
    #pragma unroll
    for (int off = 32; off > 0; off >>= 1) mx = fmaxf(mx, __shfl_down(mx, off));
    __shared__ float smx[4];
    __shared__ int scnt[4];
    __shared__ int ccount;
    if ((t & 63) == 0) smx[t >> 6] = mx;
    __syncthreads();
    float lo = 0.f;
    float hi = fmaxf(fmaxf(smx[0], smx[1]), fmaxf(smx[2], smx[3])) + 1e-6f;
    for (int it = 0; it < 14; it++) {
        float mid = 0.5f * (lo + hi);
        int c = 0;
        #pragma unroll
        for (int r = 0; r < 20; r++) c += (v[r] > mid) ? 1 : 0;
        #pragma unroll
        for (int off = 32; off > 0; off >>= 1) c += __shfl_down(c, off);
        if ((t & 63) == 0) scnt[t >> 6] = c;
        __syncthreads();
        int tot = scnt[0] + scnt[1] + scnt[2] + scnt[3];
        if (tot >= 32) lo = mid; else hi = mid;
        __syncthreads();
    }
    if (t == 0) ccount = 0;
    __syncthreads();
    // invariant: count(> lo) >= 32  =>  lo < t32 (true approx rank-32 value);
    // margin >= 10 sigma of bf16-GEMM error => true top-32 contained.
    float thr = lo - CAND_MARGIN;
    #pragma unroll
    for (int r = 0; r < 20; r++) {
        if (v[r] > thr) {
            int p = atomicAdd(&ccount, 1);
            if (p < CAND_CAP) cand_idx[(size_t)n * CAND_CAP + p] = t + 256*r;
        }
    }
    __syncthreads();
    if (t == 0) cand_cnt[n] = ccount < CAND_CAP ? ccount : CAND_CAP;
}

// ---- K4: fp64-exact recompute of candidates + ordered exact top-32 ----
// 16 lanes per candidate, 4 candidates per wave, 16 streams per block.
__global__ __launch_bounds__(256) void refine_topk(const float* __restrict__ xT,
        const float* __restrict__ Wf, const float* __restrict__ b_enc,
        const int* __restrict__ cand_idx, const int* __restrict__ cand_cnt,
        float* __restrict__ out_vals, int* __restrict__ out_idx) {
    const int n = blockIdx.x, t = threadIdx.x;
    const int lane = t & 63, w = t >> 6;
    const int sub = lane >> 4, sl = lane & 15;
    __shared__ __align__(16) float xs[IN_DIM];
    __shared__ int cidx[128];
    __shared__ float cval[128];
    __shared__ float svals[32];
    __shared__ int sidxs[32];
    const int cnt = cand_cnt[n];
    #pragma unroll
    for (int i = 0; i < 5; i++) xs[t + 256*i] = xT[(size_t)n*IN_DIM + t + 256*i];
    if (t < 128) {
        cidx[t] = (t < cnt) ? cand_idx[(size_t)n*CAND_CAP + t] : 0x7fffffff;
        cval[t] = -1.f;
    }
    __syncthreads();
    const int slot = w*4 + sub;          // 0..15
    const int iters = (cnt + 15) >> 4;
    for (int it = 0; it < iters; it++) {
        int i = it*16 + slot;
        if (i < cnt) {
            int j = cidx[i];
            const float4* wr = (const float4*)(Wf + (size_t)j * IN_DIM);
            const float4* xr = (const float4*)xs;
            double s = 0.0;
            #pragma unroll
            for (int r = 0; r < 20; r++) {
                float4 wv = wr[sl + 16*r];
                float4 xv = xr[sl + 16*r];
                s += (double)xv.x*(double)wv.x + (double)xv.y*(double)wv.y
                   + (double)xv.z*(double)wv.z + (double)xv.w*(double)wv.w;
            }
            #pragma unroll
            for (int off = 8; off > 0; off >>= 1)
                s += __shfl_down(s, off);
            if (sl == 0) {
                float fv = (float)(s + (double)b_enc[j]);
                cval[i] = fv > 0.f ? fv : 0.f;
            }
        }
    }
    __syncthreads();
    if (w == 0) {
        float v0 = cval[lane], v1 = cval[lane + 64];
        int j0 = cidx[lane], j1 = cidx[lane + 64];
        for (int it = 0; it < 32; it++) {
            bool take1 = (v1 > v0) || (v1 == v0 && j1 < j0);
            float bv = take1 ? v1 : v0;
            int bj = take1 ? j1 : j0;
            int bslot = take1 ? lane + 64 : lane;
            #pragma unroll
            for (int off = 32; off > 0; off >>= 1) {
                float ov = __shfl_down(bv, off);
                int oj = __shfl_down(bj, off);
                int os = __shfl_down(bslot, off);
                if (ov > bv || (ov == bv && oj < bj)) { bv = ov; bj = oj; bslot = os; }
            }
            bslot = __shfl(bslot, 0);
            bv = __shfl(bv, 0);
            bj = __shfl(bj, 0);
            if (lane == 0) { svals[it] = bv; sidxs[it] = bj; }
            if (bslot == lane) v0 = -1.f;
            if (bslot == lane + 64) v1 = -1.f;
        }
    }
    __syncthreads();
    if (t < 32) {
        out_vals[(size_t)n*32 + t] = svals[t];
        out_idx [(size_t)n*32 + t] = sidxs[t];
    }
}

// ---- K5: sparse decode with bf16 W_dec, uint2 gathers (4 bf16 per lane) ----
__global__ __launch_bounds__(256) void decode_kernel(const ushort_t* __restrict__ Wdec_bf,
        const float* __restrict__ b_dec, const float* __restrict__ ws_vals,
        const int* __restrict__ ws_idx, float* __restrict__ out) {
    const int bx = blockIdx.x;          // 0..511
    const int b = bx >> 4, h = bx & 15;
    const int t = threadIdx.x;
    __shared__ float lval[16][33];
    __shared__ int   lidx[16][33];
    {
        int base = (b*256 + h*16) * 32;
        for (int u = t; u < 512; u += 256) {
            lval[u >> 5][u & 31] = ws_vals[base + u];
            lidx[u >> 5][u & 31] = ws_idx[base + u];
        }
    }
    __syncthreads();
    const int w = t >> 4, cl = t & 15;
    float* o0 = out + FEATS_ELEMS + (size_t)b * XB_STRIDE + h*16 + w;
    float* o1 = o0 + RECON_ELEMS;
    for (int c0 = 0; c0 < IN_DIM; c0 += 64) {
        int c = c0 + 4*cl;
        float a16[4] = {0.f,0.f,0.f,0.f}, a32[4] = {0.f,0.f,0.f,0.f};
        #pragma unroll
        for (int j = 0; j < 32; j++) {
            uint2 p = *(const uint2*)&Wdec_bf[(size_t)lidx[w][j] * IN_DIM + c];
            float w0 = __uint_as_float(p.x << 16);
            float w1 = __uint_as_float(p.x & 0xffff0000u);
            float w2 = __uint_as_float(p.y << 16);
            float w3 = __uint_as_float(p.y & 0xffff0000u);
            float v = lval[w][j];
            float p0 = v*w0, p1 = v*w1, p2 = v*w2, p3 = v*w3;
            if (j < 16) { a16[0]+=p0; a16[1]+=p1; a16[2]+=p2; a16[3]+=p3; }
            a32[0]+=p0; a32[1]+=p1; a32[2]+=p2; a32[3]+=p3;
        }
        #pragma unroll
        for (int q = 0; q < 4; q++) {
            float bd = b_dec[c+q];
            o0[(size_t)(c+q) * 256] = a16[q] + bd;
            o1[(size_t)(c+q) * 256] = a32[q] + bd;
        }
    }
}

// ---- K6: fused zero + scatter for the two sparse feats planes ----
// Replaces hipMemsetAsync(335.5 MB via rocclr fillBuffer, ~1.3 TB/s effective)
// + mini_scatter with one kernel doing float4 streaming zero-stores at HBM
// write peak, then in-block ordered scatter of the top-k values.
// Ordering: __syncthreads() drains vmcnt(0) before the barrier, so the
// scatter stores below are ordered after this block's zero stores in L2.
__global__ __launch_bounds__(256) void zero_scatter(const float* __restrict__ vals,
        const int* __restrict__ idx, float* __restrict__ feats) {
    const int blk = blockIdx.x;            // 0..16383
    const int copy = blk >> 13;            // 0: k=16 plane, 1: k=32 plane
    const int n = blk & (NROWS - 1);
    float* row = feats + (size_t)copy * NROWS * HID + (size_t)n * HID;
    const int t = threadIdx.x;
    const f32x4 z = {0.f, 0.f, 0.f, 0.f};
    #pragma unroll
    for (int r = 0; r < 5; r++)
        *(f32x4*)&row[(size_t)(t + 256*r) * 4] = z;
    __syncthreads();
    const int k = copy ? 32 : 16;
    if (t < k) {
        row[idx[(size_t)n*32 + t]] = vals[(size_t)n*32 + t];
    }
}

extern "C" void kernel_launch(void* const* d_in, const int* in_sizes, int n_in,
                              void* d_out, int out_size, void* d_ws, size_t ws_size,
                              hipStream_t stream) {
    const float* x     = (const float*)d_in[0];
    const float* W_enc = (const float*)d_in[1];
    const float* b_enc = (const float*)d_in[2];
    const float* W_dec = (const float*)d_in[3];
    const float* b_dec = (const float*)d_in[4];
    float* out = (float*)d_out;

    float* feats0 = out;                                   // [8192][5120]
    float* feats1 = out + (size_t)NROWS * HID;             // [8192][5120]
    float* recon0 = out + FEATS_ELEMS;                     // 10.5M floats
    float* recon1 = recon0 + RECON_ELEMS;                  // 10.5M floats

    // stashes inside not-yet-final output regions:
    ushort_t* Abf = (ushort_t*)recon0;                                   // 21.0 MB
    ushort_t* Wbf = (ushort_t*)recon0 + (size_t)NROWS * IN_DIM;          // 13.1 MB (tot 34.1 < 41.9)
    float*    Wf  = recon1;                                              // 26.2 MB < 41.9
    float*    xT  = feats1;                                              // 41.9 MB < 167.8
    int* cand_idx = (int*)(feats1 + (size_t)16*1024*1024);               // 64MB into feats1
    int* cand_cnt = cand_idx + (size_t)NROWS * CAND_CAP;
    ushort_t* Wdec_bf = (ushort_t*)feats0;   // valid after topk_approx, until zero_scatter

    float* ws_vals = (float*)d_ws;                          // 8192*32 floats
    int*   ws_idx  = (int*)d_ws + (size_t)NROWS * 32;       // 8192*32 ints

    convertA<<<dim3(IN_DIM/32, HW/32, 32), 256, 0, stream>>>(x, Abf, xT);
    convertB<<<dim3(HID/32, IN_DIM/32), 256, 0, stream>>>(W_enc, Wbf, Wf);
    encode_mfma<<<dim3(HID/BN, NROWS/BM), 256, 0, stream>>>(Abf, Wbf, b_enc, feats0);
    topk_approx<<<NROWS, 256, 0, stream>>>(feats0, cand_idx, cand_cnt);
    convert_Wdec<<<(HID*IN_DIM)/(256*4), 256, 0, stream>>>(W_dec, Wdec_bf);
    refine_topk<<<NROWS, 256, 0, stream>>>(xT, Wf, b_enc, cand_idx, cand_cnt, ws_vals, ws_idx);
    decode_kernel<<<512, 256, 0, stream>>>(Wdec_bf, b_dec, ws_vals, ws_idx, out);
    zero_scatter<<<2*NROWS, 256, 0, stream>>>(ws_vals, ws_idx, out);
}

// Round 2
// 981.402 us; speedup vs baseline: 1.0748x; 1.0625x over previous
//
#include <hip/hip_runtime.h>
#include <stdint.h>

#define IN_DIM 1280
#define HID    5120
#define NROWS  8192        // 32*16*16
#define HW     256
#define XB_STRIDE (IN_DIM*HW)             // 327680
#define FEATS_ELEMS (2ull*NROWS*HID)      // 83886080 floats
#define RECON_ELEMS ((size_t)NROWS*IN_DIM) // 10485760 floats

#define CAND_CAP 80
#define CAND_MARGIN 0.015f

typedef __attribute__((ext_vector_type(8))) short bf16x8;
typedef __attribute__((ext_vector_type(4))) float f32x4;
typedef unsigned short ushort_t;

__device__ inline ushort_t f32_to_bf16(float f) {
    uint32_t u = __float_as_uint(f);
    u += 0x7fff + ((u >> 16) & 1);            // round-to-nearest-even
    return (ushort_t)(u >> 16);
}

__device__ inline void load_lds16(const void* g, void* l) {
    __builtin_amdgcn_global_load_lds(
        (const __attribute__((address_space(1))) uint32_t*)g,
        (__attribute__((address_space(3))) uint32_t*)l, 16, 0, 0);
}

// ---- K1 (merged): all input conversions in one dispatch ----
// Section A: x [32][1280][256] -> A_bf16 [n][c] + xT fp32 [n][c]   (10240 blocks)
// Section B: W_enc [1280][5120] -> W_encT bf16 + fp32 [j][c]       (6400 blocks)
// Section C: W_dec [5120][1280] fp32 -> bf16 elementwise           (6400 blocks)
#define NBLK_A 10240
#define NBLK_B 6400
#define NBLK_C 6400

__global__ __launch_bounds__(256) void convert_all(const float* __restrict__ x,
        const float* __restrict__ W_enc, const float* __restrict__ W_dec,
        ushort_t* __restrict__ Abf, float* __restrict__ xT,
        ushort_t* __restrict__ Wbf, float* __restrict__ Wf,
        ushort_t* __restrict__ Wdec_bf) {
    __shared__ float s[32][33];
    const int bid = blockIdx.x;
    const int tx = threadIdx.x & 31, ty0 = threadIdx.x >> 5;
    if (bid < NBLK_A) {
        const int c0 = (bid % 40) * 32, hw0 = ((bid / 40) & 7) * 32, b = bid / 320;
        const float* src = x + (size_t)b * XB_STRIDE;
        #pragma unroll
        for (int r = 0; r < 4; r++) {
            int c = c0 + ty0*4 + r;
            s[ty0*4+r][tx] = src[(size_t)c * HW + hw0 + tx];
        }
        __syncthreads();
        #pragma unroll
        for (int r = 0; r < 4; r++) {
            int hw = hw0 + ty0*4 + r;
            int n = b*256 + hw;
            float v = s[tx][ty0*4+r];
            Abf[(size_t)n * IN_DIM + c0 + tx] = f32_to_bf16(v);
            xT [(size_t)n * IN_DIM + c0 + tx] = v;
        }
    } else if (bid < NBLK_A + NBLK_B) {
        const int b2 = bid - NBLK_A;
        const int j0 = (b2 % 160) * 32, c0 = (b2 / 160) * 32;
        #pragma unroll
        for (int r = 0; r < 4; r++) {
            int c = c0 + ty0*4 + r;
            s[ty0*4+r][tx] = W_enc[(size_t)c * HID + j0 + tx];
        }
        __syncthreads();
        #pragma unroll
        for (int r = 0; r < 4; r++) {
            int j = j0 + ty0*4 + r;
            float v = s[tx][ty0*4+r];
            Wbf[(size_t)j * IN_DIM + c0 + tx] = f32_to_bf16(v);
            Wf [(size_t)j * IN_DIM + c0 + tx] = v;
        }
    } else {
        const int b3 = bid - NBLK_A - NBLK_B;
        size_t i = ((size_t)b3 * 256 + threadIdx.x) * 4;
        float4 v = *(const float4*)&W_dec[i];
        Wdec_bf[i+0] = f32_to_bf16(v.x);
        Wdec_bf[i+1] = f32_to_bf16(v.y);
        Wdec_bf[i+2] = f32_to_bf16(v.z);
        Wdec_bf[i+3] = f32_to_bf16(v.w);
    }
}

// ---- K2: bf16 MFMA GEMM, approx enc = relu(A@W + b), global_load_lds staging ----
#define BM 128
#define BN 128
#define BK 32

__global__ __launch_bounds__(256) void encode_mfma(const ushort_t* __restrict__ A,
        const ushort_t* __restrict__ B, const float* __restrict__ b_enc,
        float* __restrict__ C) {
    __shared__ __align__(16) ushort_t As[BM*BK];   // [128 rows][32 k] = 8 KB
    __shared__ __align__(16) ushort_t Bs[BN*BK];
    const int n0 = blockIdx.x * BN;
    const int m0 = blockIdx.y * BM;
    const int t = threadIdx.x;
    const int lane = t & 63, w = t >> 6;
    const int mr0 = (w >> 1) * 64, nc0 = (w & 1) * 64;
    const int lm = lane & 15, lq = lane >> 4;
    const int srow_l = w*16 + (lane >> 2);
    const int skof   = (lane & 3) * 8;

    f32x4 acc[4][4];
    #pragma unroll
    for (int i = 0; i < 4; i++)
        #pragma unroll
        for (int j = 0; j < 4; j++)
            #pragma unroll
            for (int q = 0; q < 4; q++) acc[i][j][q] = 0.f;

    for (int k0 = 0; k0 < IN_DIM; k0 += BK) {
        #pragma unroll
        for (int h = 0; h < 2; h++) {
            const ushort_t* ga = &A[(size_t)(m0 + h*64 + srow_l)*IN_DIM + k0 + skof];
            const ushort_t* gb = &B[(size_t)(n0 + h*64 + srow_l)*IN_DIM + k0 + skof];
            load_lds16(ga, &As[(h*64 + w*16)*BK]);
            load_lds16(gb, &Bs[(h*64 + w*16)*BK]);
        }
        __syncthreads();
        bf16x8 af[4], bfr[4];
        #pragma unroll
        for (int mt = 0; mt < 4; mt++)
            af[mt] = *(const bf16x8*)&As[(mr0 + mt*16 + lm)*BK + lq*8];
        #pragma unroll
        for (int nt = 0; nt < 4; nt++)
            bfr[nt] = *(const bf16x8*)&Bs[(nc0 + nt*16 + lm)*BK + lq*8];
        #pragma unroll
        for (int mt = 0; mt < 4; mt++)
            #pragma unroll
            for (int nt = 0; nt < 4; nt++)
                acc[mt][nt] = __builtin_amdgcn_mfma_f32_16x16x32_bf16(af[mt], bfr[nt], acc[mt][nt], 0, 0, 0);
        __syncthreads();
    }
    #pragma unroll
    for (int mt = 0; mt < 4; mt++) {
        #pragma unroll
        for (int nt = 0; nt < 4; nt++) {
            int col = n0 + nc0 + nt*16 + lm;
            float bias = b_enc[col];
            #pragma unroll
            for (int r = 0; r < 4; r++) {
                int row = m0 + mr0 + mt*16 + lq*4 + r;
                float v = acc[mt][nt][r] + bias;
                C[(size_t)row*HID + col] = v > 0.f ? v : 0.f;
            }
        }
    }
}

// ---- K3: per-row approx-rank-32 threshold (ballot binary search) + compaction ----
__global__ __launch_bounds__(256) void topk_approx(const float* __restrict__ E,
        int* __restrict__ cand_idx, int* __restrict__ cand_cnt) {
    const int n = blockIdx.x, t = threadIdx.x;
    const float* row = E + (size_t)n * HID;
    float v[20];
    #pragma unroll
    for (int r = 0; r < 20; r++) v[r] = row[t + 256*r];
    float mx = 0.f;
    #pragma unroll
    for (int r = 0; r < 20; r++) mx = fmaxf(mx, v[r]);
    #pragma unroll
    for (int off = 32; off > 0; off >>= 1) mx = fmaxf(mx, __shfl_down(mx, off));
    __shared__ float smx[4];
    __shared__ int scnt[2][4];
    __shared__ int ccount;
    if ((t & 63) == 0) smx[t >> 6] = mx;
    if (t == 0) ccount = 0;
    __syncthreads();
    float lo = 0.f;
    float hi = fmaxf(fmaxf(smx[0], smx[1]), fmaxf(smx[2], smx[3])) + 1e-6f;
    // 11 iterations: interval <= hi/2048 ~ 0.0012 << CAND_MARGIN.
    // wave-uniform counting: v_cmp -> 64-bit ballot -> scalar popcount.
    for (int it = 0; it < 11; it++) {
        float mid = 0.5f * (lo + hi);
        int c = 0;
        #pragma unroll
        for (int r = 0; r < 20; r++)
            c += (int)__popcll(__ballot(v[r] > mid));
        if ((t & 63) == 0) scnt[it & 1][t >> 6] = c;
        __syncthreads();
        int tot = scnt[it & 1][0] + scnt[it & 1][1] + scnt[it & 1][2] + scnt[it & 1][3];
        if (tot >= 32) lo = mid; else hi = mid;
        // no second barrier: next iter writes the other scnt buffer
    }
    // invariant: count(> lo) >= 32  =>  lo < t32 (true approx rank-32 value);
    // margin >= 10 sigma of bf16-GEMM error => true top-32 contained.
    float thr = lo - CAND_MARGIN;
    #pragma unroll
    for (int r = 0; r < 20; r++) {
        if (v[r] > thr) {
            int p = atomicAdd(&ccount, 1);
            if (p < CAND_CAP) cand_idx[(size_t)n * CAND_CAP + p] = t + 256*r;
        }
    }
    __syncthreads();
    if (t == 0) cand_cnt[n] = ccount < CAND_CAP ? ccount : CAND_CAP;
}

// ---- K4: fp32 exact-enough recompute of candidates + ordered exact top-32 ----
// 16 lanes per candidate, 4 candidates per wave, 16 streams per block.
// fp32 4-accumulator dot: error ~1e-6 << rank-32/33 gap (~6e-3) => selection
// identical to fp32 jax reference w.h.p. (same argument as previous fp64 path).
__global__ __launch_bounds__(256) void refine_topk(const float* __restrict__ xT,
        const float* __restrict__ Wf, const float* __restrict__ b_enc,
        const int* __restrict__ cand_idx, const int* __restrict__ cand_cnt,
        float* __restrict__ out_vals, int* __restrict__ out_idx) {
    const int n = blockIdx.x, t = threadIdx.x;
    const int lane = t & 63, w = t >> 6;
    const int sub = lane >> 4, sl = lane & 15;
    __shared__ __align__(16) float xs[IN_DIM];
    __shared__ int cidx[128];
    __shared__ float cval[128];
    __shared__ float svals[32];
    __shared__ int sidxs[32];
    const int cnt = cand_cnt[n];
    #pragma unroll
    for (int i = 0; i < 5; i++) xs[t + 256*i] = xT[(size_t)n*IN_DIM + t + 256*i];
    if (t < 128) {
        cidx[t] = (t < cnt) ? cand_idx[(size_t)n*CAND_CAP + t] : 0x7fffffff;
        cval[t] = -1.f;
    }
    __syncthreads();
    const int slot = w*4 + sub;          // 0..15
    const int iters = (cnt + 15) >> 4;
    for (int it = 0; it < iters; it++) {
        int i = it*16 + slot;
        if (i < cnt) {
            int j = cidx[i];
            const float4* wr = (const float4*)(Wf + (size_t)j * IN_DIM);
            const float4* xr = (const float4*)xs;
            float a0 = 0.f, a1 = 0.f, a2 = 0.f, a3 = 0.f;
            #pragma unroll
            for (int r = 0; r < 20; r++) {
                float4 wv = wr[sl + 16*r];
                float4 xv = xr[sl + 16*r];
                a0 = fmaf(xv.x, wv.x, a0);
                a1 = fmaf(xv.y, wv.y, a1);
                a2 = fmaf(xv.z, wv.z, a2);
                a3 = fmaf(xv.w, wv.w, a3);
            }
            float s = (a0 + a1) + (a2 + a3);
            #pragma unroll
            for (int off = 8; off > 0; off >>= 1)
                s += __shfl_down(s, off);
            if (sl == 0) {
                float fv = s + b_enc[j];
                cval[i] = fv > 0.f ? fv : 0.f;
            }
        }
    }
    __syncthreads();
    if (w == 0) {
        float v0 = cval[lane], v1 = cval[lane + 64];
        int j0 = cidx[lane], j1 = cidx[lane + 64];
        for (int it = 0; it < 32; it++) {
            bool take1 = (v1 > v0) || (v1 == v0 && j1 < j0);
            float bv = take1 ? v1 : v0;
            int bj = take1 ? j1 : j0;
            int bslot = take1 ? lane + 64 : lane;
            #pragma unroll
            for (int off = 32; off > 0; off >>= 1) {
                float ov = __shfl_down(bv, off);
                int oj = __shfl_down(bj, off);
                int os = __shfl_down(bslot, off);
                if (ov > bv || (ov == bv && oj < bj)) { bv = ov; bj = oj; bslot = os; }
            }
            bslot = __shfl(bslot, 0);
            bv = __shfl(bv, 0);
            bj = __shfl(bj, 0);
            if (lane == 0) { svals[it] = bv; sidxs[it] = bj; }
            if (bslot == lane) v0 = -1.f;
            if (bslot == lane + 64) v1 = -1.f;
        }
    }
    __syncthreads();
    if (t < 32) {
        out_vals[(size_t)n*32 + t] = svals[t];
        out_idx [(size_t)n*32 + t] = sidxs[t];
    }
}

// ---- K5: sparse decode with bf16 W_dec, uint2 gathers (4 bf16 per lane) ----
__global__ __launch_bounds__(256) void decode_kernel(const ushort_t* __restrict__ Wdec_bf,
        const float* __restrict__ b_dec, const float* __restrict__ ws_vals,
        const int* __restrict__ ws_idx, float* __restrict__ out) {
    const int bx = blockIdx.x;          // 0..511
    const int b = bx >> 4, h = bx & 15;
    const int t = threadIdx.x;
    __shared__ float lval[16][33];
    __shared__ int   lidx[16][33];
    {
        int base = (b*256 + h*16) * 32;
        for (int u = t; u < 512; u += 256) {
            lval[u >> 5][u & 31] = ws_vals[base + u];
            lidx[u >> 5][u & 31] = ws_idx[base + u];
        }
    }
    __syncthreads();
    const int w = t >> 4, cl = t & 15;
    float* o0 = out + FEATS_ELEMS + (size_t)b * XB_STRIDE + h*16 + w;
    float* o1 = o0 + RECON_ELEMS;
    for (int c0 = 0; c0 < IN_DIM; c0 += 64) {
        int c = c0 + 4*cl;
        float a16[4] = {0.f,0.f,0.f,0.f}, a32[4] = {0.f,0.f,0.f,0.f};
        #pragma unroll
        for (int j = 0; j < 32; j++) {
            uint2 p = *(const uint2*)&Wdec_bf[(size_t)lidx[w][j] * IN_DIM + c];
            float w0 = __uint_as_float(p.x << 16);
            float w1 = __uint_as_float(p.x & 0xffff0000u);
            float w2 = __uint_as_float(p.y << 16);
            float w3 = __uint_as_float(p.y & 0xffff0000u);
            float v = lval[w][j];
            float p0 = v*w0, p1 = v*w1, p2 = v*w2, p3 = v*w3;
            if (j < 16) { a16[0]+=p0; a16[1]+=p1; a16[2]+=p2; a16[3]+=p3; }
            a32[0]+=p0; a32[1]+=p1; a32[2]+=p2; a32[3]+=p3;
        }
        #pragma unroll
        for (int q = 0; q < 4; q++) {
            float bd = b_dec[c+q];
            o0[(size_t)(c+q) * 256] = a16[q] + bd;
            o1[(size_t)(c+q) * 256] = a32[q] + bd;
        }
    }
}

// ---- K6: fused zero + scatter for the two sparse feats planes ----
__global__ __launch_bounds__(256) void zero_scatter(const float* __restrict__ vals,
        const int* __restrict__ idx, float* __restrict__ feats) {
    const int blk = blockIdx.x;            // 0..16383
    const int copy = blk >> 13;            // 0: k=16 plane, 1: k=32 plane
    const int n = blk & (NROWS - 1);
    float* row = feats + (size_t)copy * NROWS * HID + (size_t)n * HID;
    const int t = threadIdx.x;
    const f32x4 z = {0.f, 0.f, 0.f, 0.f};
    #pragma unroll
    for (int r = 0; r < 5; r++)
        *(f32x4*)&row[(size_t)(t + 256*r) * 4] = z;
    __syncthreads();
    const int k = copy ? 32 : 16;
    if (t < k) {
        row[idx[(size_t)n*32 + t]] = vals[(size_t)n*32 + t];
    }
}

extern "C" void kernel_launch(void* const* d_in, const int* in_sizes, int n_in,
                              void* d_out, int out_size, void* d_ws, size_t ws_size,
                              hipStream_t stream) {
    const float* x     = (const float*)d_in[0];
    const float* W_enc = (const float*)d_in[1];
    const float* b_enc = (const float*)d_in[2];
    const float* W_dec = (const float*)d_in[3];
    const float* b_dec = (const float*)d_in[4];
    float* out = (float*)d_out;

    float* feats0 = out;                                   // [8192][5120]
    float* feats1 = out + (size_t)NROWS * HID;             // [8192][5120]
    float* recon0 = out + FEATS_ELEMS;                     // 10.5M floats
    float* recon1 = recon0 + RECON_ELEMS;                  // 10.5M floats

    // stashes inside not-yet-final output regions:
    ushort_t* Abf = (ushort_t*)recon0;                                   // 21.0 MB
    ushort_t* Wbf = (ushort_t*)recon0 + (size_t)NROWS * IN_DIM;          // 13.1 MB (tot 34.1 < 41.9)
    float*    Wf  = recon1;                                              // 26.2 MB < 41.9
    float*    xT  = feats1;                                              // 41.9 MB (feats1[0..10.5M floats))
    // Wdec_bf moved into feats1 at +48 MB: xT ends at 41.9 MB, cand_idx starts
    // at 64 MB, Wdec_bf spans 48..61.1 MB -> no overlap; dead before zero_scatter.
    ushort_t* Wdec_bf = (ushort_t*)(feats1 + (size_t)12*1024*1024);
    int* cand_idx = (int*)(feats1 + (size_t)16*1024*1024);               // 64MB into feats1
    int* cand_cnt = cand_idx + (size_t)NROWS * CAND_CAP;

    float* ws_vals = (float*)d_ws;                          // 8192*32 floats
    int*   ws_idx  = (int*)d_ws + (size_t)NROWS * 32;       // 8192*32 ints

    convert_all<<<NBLK_A + NBLK_B + NBLK_C, 256, 0, stream>>>(
        x, W_enc, W_dec, Abf, xT, Wbf, Wf, Wdec_bf);
    encode_mfma<<<dim3(HID/BN, NROWS/BM), 256, 0, stream>>>(Abf, Wbf, b_enc, feats0);
    topk_approx<<<NROWS, 256, 0, stream>>>(feats0, cand_idx, cand_cnt);
    refine_topk<<<NROWS, 256, 0, stream>>>(xT, Wf, b_enc, cand_idx, cand_cnt, ws_vals, ws_idx);
    decode_kernel<<<512, 256, 0, stream>>>(Wdec_bf, b_dec, ws_vals, ws_idx, out);
    zero_scatter<<<2*NROWS, 256, 0, stream>>>(ws_vals, ws_idx, out);
}

// Round 3
// 929.242 us; speedup vs baseline: 1.1351x; 1.0561x over previous
//
#include <hip/hip_runtime.h>
#include <stdint.h>

#define IN_DIM 1280
#define HID    5120
#define NROWS  8192        // 32*16*16
#define HW     256
#define XB_STRIDE (IN_DIM*HW)             // 327680
#define FEATS_ELEMS (2ull*NROWS*HID)      // 83886080 floats
#define RECON_ELEMS ((size_t)NROWS*IN_DIM) // 10485760 floats

#define CAND_CAP 80
// margin > 2*(gemm bf16 err + bf16 storage half-ulp @ v~1.5) = 2*(0.0075+0.0039)
#define CAND_MARGIN 0.024f

typedef __attribute__((ext_vector_type(8))) short bf16x8;
typedef __attribute__((ext_vector_type(4))) float f32x4;
typedef unsigned short ushort_t;

__device__ inline ushort_t f32_to_bf16(float f) {
    uint32_t u = __float_as_uint(f);
    u += 0x7fff + ((u >> 16) & 1);            // round-to-nearest-even
    return (ushort_t)(u >> 16);
}

__device__ inline float bf16_to_f32(ushort_t h) {
    return __uint_as_float((uint32_t)h << 16);
}

__device__ inline void load_lds16(const void* g, void* l) {
    __builtin_amdgcn_global_load_lds(
        (const __attribute__((address_space(1))) uint32_t*)g,
        (__attribute__((address_space(3))) uint32_t*)l, 16, 0, 0);
}

// ---- K1 (merged): all input conversions in one dispatch ----
#define NBLK_A 10240
#define NBLK_B 6400
#define NBLK_C 6400

__global__ __launch_bounds__(256) void convert_all(const float* __restrict__ x,
        const float* __restrict__ W_enc, const float* __restrict__ W_dec,
        ushort_t* __restrict__ Abf, float* __restrict__ xT,
        ushort_t* __restrict__ Wbf, float* __restrict__ Wf,
        ushort_t* __restrict__ Wdec_bf) {
    __shared__ float s[32][33];
    const int bid = blockIdx.x;
    const int tx = threadIdx.x & 31, ty0 = threadIdx.x >> 5;
    if (bid < NBLK_A) {
        const int c0 = (bid % 40) * 32, hw0 = ((bid / 40) & 7) * 32, b = bid / 320;
        const float* src = x + (size_t)b * XB_STRIDE;
        #pragma unroll
        for (int r = 0; r < 4; r++) {
            int c = c0 + ty0*4 + r;
            s[ty0*4+r][tx] = src[(size_t)c * HW + hw0 + tx];
        }
        __syncthreads();
        #pragma unroll
        for (int r = 0; r < 4; r++) {
            int hw = hw0 + ty0*4 + r;
            int n = b*256 + hw;
            float v = s[tx][ty0*4+r];
            Abf[(size_t)n * IN_DIM + c0 + tx] = f32_to_bf16(v);
            xT [(size_t)n * IN_DIM + c0 + tx] = v;
        }
    } else if (bid < NBLK_A + NBLK_B) {
        const int b2 = bid - NBLK_A;
        const int j0 = (b2 % 160) * 32, c0 = (b2 / 160) * 32;
        #pragma unroll
        for (int r = 0; r < 4; r++) {
            int c = c0 + ty0*4 + r;
            s[ty0*4+r][tx] = W_enc[(size_t)c * HID + j0 + tx];
        }
        __syncthreads();
        #pragma unroll
        for (int r = 0; r < 4; r++) {
            int j = j0 + ty0*4 + r;
            float v = s[tx][ty0*4+r];
            Wbf[(size_t)j * IN_DIM + c0 + tx] = f32_to_bf16(v);
            Wf [(size_t)j * IN_DIM + c0 + tx] = v;
        }
    } else {
        const int b3 = bid - NBLK_A - NBLK_B;
        size_t i = ((size_t)b3 * 256 + threadIdx.x) * 4;
        float4 v = *(const float4*)&W_dec[i];
        Wdec_bf[i+0] = f32_to_bf16(v.x);
        Wdec_bf[i+1] = f32_to_bf16(v.y);
        Wdec_bf[i+2] = f32_to_bf16(v.z);
        Wdec_bf[i+3] = f32_to_bf16(v.w);
    }
}

// ---- K2: bf16 MFMA GEMM, approx enc = relu(A@W + b) -> bf16 store ----
#define BM 128
#define BN 128
#define BK 32

__global__ __launch_bounds__(256) void encode_mfma(const ushort_t* __restrict__ A,
        const ushort_t* __restrict__ B, const float* __restrict__ b_enc,
        ushort_t* __restrict__ C) {
    __shared__ __align__(16) ushort_t As[BM*BK];   // [128 rows][32 k] = 8 KB
    __shared__ __align__(16) ushort_t Bs[BN*BK];
    const int n0 = blockIdx.x * BN;
    const int m0 = blockIdx.y * BM;
    const int t = threadIdx.x;
    const int lane = t & 63, w = t >> 6;
    const int mr0 = (w >> 1) * 64, nc0 = (w & 1) * 64;
    const int lm = lane & 15, lq = lane >> 4;
    const int srow_l = w*16 + (lane >> 2);
    const int skof   = (lane & 3) * 8;

    f32x4 acc[4][4];
    #pragma unroll
    for (int i = 0; i < 4; i++)
        #pragma unroll
        for (int j = 0; j < 4; j++)
            #pragma unroll
            for (int q = 0; q < 4; q++) acc[i][j][q] = 0.f;

    for (int k0 = 0; k0 < IN_DIM; k0 += BK) {
        #pragma unroll
        for (int h = 0; h < 2; h++) {
            const ushort_t* ga = &A[(size_t)(m0 + h*64 + srow_l)*IN_DIM + k0 + skof];
            const ushort_t* gb = &B[(size_t)(n0 + h*64 + srow_l)*IN_DIM + k0 + skof];
            load_lds16(ga, &As[(h*64 + w*16)*BK]);
            load_lds16(gb, &Bs[(h*64 + w*16)*BK]);
        }
        __syncthreads();
        bf16x8 af[4], bfr[4];
        #pragma unroll
        for (int mt = 0; mt < 4; mt++)
            af[mt] = *(const bf16x8*)&As[(mr0 + mt*16 + lm)*BK + lq*8];
        #pragma unroll
        for (int nt = 0; nt < 4; nt++)
            bfr[nt] = *(const bf16x8*)&Bs[(nc0 + nt*16 + lm)*BK + lq*8];
        #pragma unroll
        for (int mt = 0; mt < 4; mt++)
            #pragma unroll
            for (int nt = 0; nt < 4; nt++)
                acc[mt][nt] = __builtin_amdgcn_mfma_f32_16x16x32_bf16(af[mt], bfr[nt], acc[mt][nt], 0, 0, 0);
        __syncthreads();
    }
    #pragma unroll
    for (int mt = 0; mt < 4; mt++) {
        #pragma unroll
        for (int nt = 0; nt < 4; nt++) {
            int col = n0 + nc0 + nt*16 + lm;
            float bias = b_enc[col];
            #pragma unroll
            for (int r = 0; r < 4; r++) {
                int row = m0 + mr0 + mt*16 + lq*4 + r;
                float v = acc[mt][nt][r] + bias;
                C[(size_t)row*HID + col] = f32_to_bf16(v > 0.f ? v : 0.f);
            }
        }
    }
}

// ---- K3: per-row approx-rank-32 threshold (ballot binary search) on bf16 enc ----
__global__ __launch_bounds__(256) void topk_approx(const ushort_t* __restrict__ E,
        int* __restrict__ cand_idx, int* __restrict__ cand_cnt) {
    const int n = blockIdx.x, t = threadIdx.x;
    const ushort_t* row = E + (size_t)n * HID;
    // vectorized loads; thread<->element mapping is arbitrary (ballot counting).
    // r<16: idx = 16*t + r ; r>=16: idx = 4096 + 4*t + (r-16)
    float v[20];
    {
        bf16x8 u0 = *(const bf16x8*)&row[t*16];
        bf16x8 u1 = *(const bf16x8*)&row[t*16 + 8];
        #pragma unroll
        for (int r = 0; r < 8; r++) {
            v[r]   = bf16_to_f32((ushort_t)u0[r]);
            v[r+8] = bf16_to_f32((ushort_t)u1[r]);
        }
        ushort_t u2[4];
        *(uint2*)u2 = *(const uint2*)&row[4096 + t*4];
        #pragma unroll
        for (int r = 0; r < 4; r++) v[16+r] = bf16_to_f32(u2[r]);
    }
    float mx = 0.f;
    #pragma unroll
    for (int r = 0; r < 20; r++) mx = fmaxf(mx, v[r]);
    #pragma unroll
    for (int off = 32; off > 0; off >>= 1) mx = fmaxf(mx, __shfl_down(mx, off));
    __shared__ float smx[4];
    __shared__ int scnt[2][4];
    __shared__ int ccount;
    if ((t & 63) == 0) smx[t >> 6] = mx;
    if (t == 0) ccount = 0;
    __syncthreads();
    float lo = 0.f;
    float hi = fmaxf(fmaxf(smx[0], smx[1]), fmaxf(smx[2], smx[3])) + 1e-6f;
    for (int it = 0; it < 11; it++) {
        float mid = 0.5f * (lo + hi);
        int c = 0;
        #pragma unroll
        for (int r = 0; r < 20; r++)
            c += (int)__popcll(__ballot(v[r] > mid));
        if ((t & 63) == 0) scnt[it & 1][t >> 6] = c;
        __syncthreads();
        int tot = scnt[it & 1][0] + scnt[it & 1][1] + scnt[it & 1][2] + scnt[it & 1][3];
        if (tot >= 32) lo = mid; else hi = mid;
    }
    float thr = lo - CAND_MARGIN;
    #pragma unroll
    for (int r = 0; r < 20; r++) {
        if (v[r] > thr) {
            int p = atomicAdd(&ccount, 1);
            int idx = (r < 16) ? (16*t + r) : (4096 + 4*t + (r - 16));
            if (p < CAND_CAP) cand_idx[(size_t)n * CAND_CAP + p] = idx;
        }
    }
    __syncthreads();
    if (t == 0) cand_cnt[n] = ccount < CAND_CAP ? ccount : CAND_CAP;
}

// ---- K4: fp32 exact-enough recompute of candidates + ordered exact top-32 ----
__global__ __launch_bounds__(256) void refine_topk(const float* __restrict__ xT,
        const float* __restrict__ Wf, const float* __restrict__ b_enc,
        const int* __restrict__ cand_idx, const int* __restrict__ cand_cnt,
        float* __restrict__ out_vals, int* __restrict__ out_idx) {
    const int n = blockIdx.x, t = threadIdx.x;
    const int lane = t & 63, w = t >> 6;
    const int sub = lane >> 4, sl = lane & 15;
    __shared__ __align__(16) float xs[IN_DIM];
    __shared__ int cidx[128];
    __shared__ float cval[128];
    __shared__ float svals[32];
    __shared__ int sidxs[32];
    const int cnt = cand_cnt[n];
    #pragma unroll
    for (int i = 0; i < 5; i++) xs[t + 256*i] = xT[(size_t)n*IN_DIM + t + 256*i];
    if (t < 128) {
        cidx[t] = (t < cnt) ? cand_idx[(size_t)n*CAND_CAP + t] : 0x7fffffff;
        cval[t] = -1.f;
    }
    __syncthreads();
    const int slot = w*4 + sub;          // 0..15
    const int iters = (cnt + 15) >> 4;
    for (int it = 0; it < iters; it++) {
        int i = it*16 + slot;
        if (i < cnt) {
            int j = cidx[i];
            const float4* wr = (const float4*)(Wf + (size_t)j * IN_DIM);
            const float4* xr = (const float4*)xs;
            float a0 = 0.f, a1 = 0.f, a2 = 0.f, a3 = 0.f;
            #pragma unroll
            for (int r = 0; r < 20; r++) {
                float4 wv = wr[sl + 16*r];
                float4 xv = xr[sl + 16*r];
                a0 = fmaf(xv.x, wv.x, a0);
                a1 = fmaf(xv.y, wv.y, a1);
                a2 = fmaf(xv.z, wv.z, a2);
                a3 = fmaf(xv.w, wv.w, a3);
            }
            float s = (a0 + a1) + (a2 + a3);
            #pragma unroll
            for (int off = 8; off > 0; off >>= 1)
                s += __shfl_down(s, off);
            if (sl == 0) {
                float fv = s + b_enc[j];
                cval[i] = fv > 0.f ? fv : 0.f;
            }
        }
    }
    __syncthreads();
    if (w == 0) {
        float v0 = cval[lane], v1 = cval[lane + 64];
        int j0 = cidx[lane], j1 = cidx[lane + 64];
        for (int it = 0; it < 32; it++) {
            bool take1 = (v1 > v0) || (v1 == v0 && j1 < j0);
            float bv = take1 ? v1 : v0;
            int bj = take1 ? j1 : j0;
            int bslot = take1 ? lane + 64 : lane;
            #pragma unroll
            for (int off = 32; off > 0; off >>= 1) {
                float ov = __shfl_down(bv, off);
                int oj = __shfl_down(bj, off);
                int os = __shfl_down(bslot, off);
                if (ov > bv || (ov == bv && oj < bj)) { bv = ov; bj = oj; bslot = os; }
            }
            bslot = __shfl(bslot, 0);
            bv = __shfl(bv, 0);
            bj = __shfl(bj, 0);
            if (lane == 0) { svals[it] = bv; sidxs[it] = bj; }
            if (bslot == lane) v0 = -1.f;
            if (bslot == lane + 64) v1 = -1.f;
        }
    }
    __syncthreads();
    if (t < 32) {
        out_vals[(size_t)n*32 + t] = svals[t];
        out_idx [(size_t)n*32 + t] = sidxs[t];
    }
}

// ---- K5: sparse decode; gathers stay cl-coalesced, stores staged via LDS ----
// Old path stored single dwords at 1KB lane stride (16B segments, ~4x write
// amplification). Now each 64-col chunk is staged in LDS and written as
// full 64B line segments (4 lanes x float4 per c).
__global__ __launch_bounds__(256) void decode_kernel(const ushort_t* __restrict__ Wdec_bf,
        const float* __restrict__ b_dec, const float* __restrict__ ws_vals,
        const int* __restrict__ ws_idx, float* __restrict__ out) {
    const int bx = blockIdx.x;          // 0..511
    const int b = bx >> 4, h = bx & 15;
    const int t = threadIdx.x;
    __shared__ float lval[16][33];
    __shared__ int   lidx[16][33];
    __shared__ float s16[16][64];
    __shared__ float s32[16][64];
    {
        int base = (b*256 + h*16) * 32;
        for (int u = t; u < 512; u += 256) {
            lval[u >> 5][u & 31] = ws_vals[base + u];
            lidx[u >> 5][u & 31] = ws_idx[base + u];
        }
    }
    __syncthreads();
    const int w = t >> 4, cl = t & 15;
    const int c_loc = t >> 2, wq = (t & 3) * 4;
    float* o0 = out + FEATS_ELEMS + (size_t)b * XB_STRIDE + h*16;
    float* o1 = o0 + RECON_ELEMS;
    for (int c0 = 0; c0 < IN_DIM; c0 += 64) {
        int c = c0 + 4*cl;
        float a16[4] = {0.f,0.f,0.f,0.f}, a32[4] = {0.f,0.f,0.f,0.f};
        #pragma unroll
        for (int j = 0; j < 32; j++) {
            uint2 p = *(const uint2*)&Wdec_bf[(size_t)lidx[w][j] * IN_DIM + c];
            float w0 = __uint_as_float(p.x << 16);
            float w1 = __uint_as_float(p.x & 0xffff0000u);
            float w2 = __uint_as_float(p.y << 16);
            float w3 = __uint_as_float(p.y & 0xffff0000u);
            float v = lval[w][j];
            float p0 = v*w0, p1 = v*w1, p2 = v*w2, p3 = v*w3;
            if (j < 16) { a16[0]+=p0; a16[1]+=p1; a16[2]+=p2; a16[3]+=p3; }
            a32[0]+=p0; a32[1]+=p1; a32[2]+=p2; a32[3]+=p3;
        }
        f32x4 t16, t32;
        #pragma unroll
        for (int q = 0; q < 4; q++) {
            float bd = b_dec[c+q];
            t16[q] = a16[q] + bd;
            t32[q] = a32[q] + bd;
        }
        *(f32x4*)&s16[w][4*cl] = t16;
        *(f32x4*)&s32[w][4*cl] = t32;
        __syncthreads();
        f32x4 r16, r32;
        #pragma unroll
        for (int i = 0; i < 4; i++) {
            r16[i] = s16[wq + i][c_loc];
            r32[i] = s32[wq + i][c_loc];
        }
        *(f32x4*)&o0[(size_t)(c0 + c_loc)*256 + wq] = r16;
        *(f32x4*)&o1[(size_t)(c0 + c_loc)*256 + wq] = r32;
        __syncthreads();
    }
}

// ---- K6: fused zero + scatter for the two sparse feats planes ----
__global__ __launch_bounds__(256) void zero_scatter(const float* __restrict__ vals,
        const int* __restrict__ idx, float* __restrict__ feats) {
    const int blk = blockIdx.x;            // 0..16383
    const int copy = blk >> 13;            // 0: k=16 plane, 1: k=32 plane
    const int n = blk & (NROWS - 1);
    float* row = feats + (size_t)copy * NROWS * HID + (size_t)n * HID;
    const int t = threadIdx.x;
    const f32x4 z = {0.f, 0.f, 0.f, 0.f};
    #pragma unroll
    for (int r = 0; r < 5; r++)
        *(f32x4*)&row[(size_t)(t + 256*r) * 4] = z;
    __syncthreads();
    const int k = copy ? 32 : 16;
    if (t < k) {
        row[idx[(size_t)n*32 + t]] = vals[(size_t)n*32 + t];
    }
}

extern "C" void kernel_launch(void* const* d_in, const int* in_sizes, int n_in,
                              void* d_out, int out_size, void* d_ws, size_t ws_size,
                              hipStream_t stream) {
    const float* x     = (const float*)d_in[0];
    const float* W_enc = (const float*)d_in[1];
    const float* b_enc = (const float*)d_in[2];
    const float* W_dec = (const float*)d_in[3];
    const float* b_dec = (const float*)d_in[4];
    float* out = (float*)d_out;

    float* feats0 = out;                                   // [8192][5120]
    float* feats1 = out + (size_t)NROWS * HID;             // [8192][5120]
    float* recon0 = out + FEATS_ELEMS;                     // 10.5M floats
    float* recon1 = recon0 + RECON_ELEMS;                  // 10.5M floats

    // stashes inside not-yet-final output regions:
    ushort_t* Abf = (ushort_t*)recon0;                                   // 21.0 MB
    ushort_t* Wbf = (ushort_t*)recon0 + (size_t)NROWS * IN_DIM;          // 13.1 MB (tot 34.1 < 41.9)
    float*    Wf  = recon1;                                              // 26.2 MB < 41.9
    float*    xT  = feats1;                                              // feats1[0 .. 41.9 MB)
    // enc bf16 lives in feats0[0 .. 83.9 MB); Wdec_bf at feats0 + 88 MB (13.1 MB)
    ushort_t* enc_bf  = (ushort_t*)feats0;
    ushort_t* Wdec_bf = (ushort_t*)(out + (size_t)22*1024*1024);
    int* cand_idx = (int*)(feats1 + (size_t)16*1024*1024);               // 64MB into feats1
    int* cand_cnt = cand_idx + (size_t)NROWS * CAND_CAP;

    float* ws_vals = (float*)d_ws;                          // 8192*32 floats
    int*   ws_idx  = (int*)d_ws + (size_t)NROWS * 32;       // 8192*32 ints

    convert_all<<<NBLK_A + NBLK_B + NBLK_C, 256, 0, stream>>>(
        x, W_enc, W_dec, Abf, xT, Wbf, Wf, Wdec_bf);
    encode_mfma<<<dim3(HID/BN, NROWS/BM), 256, 0, stream>>>(Abf, Wbf, b_enc, enc_bf);
    topk_approx<<<NROWS, 256, 0, stream>>>(enc_bf, cand_idx, cand_cnt);
    refine_topk<<<NROWS, 256, 0, stream>>>(xT, Wf, b_enc, cand_idx, cand_cnt, ws_vals, ws_idx);
    decode_kernel<<<512, 256, 0, stream>>>(Wdec_bf, b_dec, ws_vals, ws_idx, out);
    zero_scatter<<<2*NROWS, 256, 0, stream>>>(ws_vals, ws_idx, out);
}